// Round 7
// baseline (150.797 us; speedup 1.0000x reference)
//
#include <hip/hip_runtime.h>
#include <hip/hip_bf16.h>

// Problem constants
#define NB    4096          // batch
#define ND    256           // dim
#define NP    2             // positives per anchor
#define TOT   (NB * 3)      // 12288 rows: [a | p0 | p1]
#define NBLK  768           // grid: 48 chunks x 16 row-blocks
#define COLS_PER_CHUNK 256
#define TILES 16
#define IMIN_SENT (-1073741824)      // mask sentinel; < any dot (|dot| <= 4.13M)
#define INV_SCALE (1.0f / 16129.0f)  // 1/(127*127)

// F2 is FRAGMENT-MAJOR i8 (R13 layout): for 16-row group g, K-block kk (64
// i8), the 1024-B block F2[g*4096 + kk*1024 + (quad*16 + r15)*16 + j] holds
// K-byte kk*64 + quad*16 + j of row g*16 + r15. Fragment loads = lane*16
// contiguous b128.
typedef float f32x4 __attribute__((ext_vector_type(4)));
typedef int   i32x4 __attribute__((ext_vector_type(4)));

// ws layout (bytes)
#define WS_F_OFF    0                             // uchar[3 MB] i8 fragment-major
#define WS_POS_OFF  (TOT * 256)                   // float[4096*2] pos distances
#define WS_NEG_OFF  (WS_POS_OFF + NB * NP * 4)    // int[3][4096] neg-dot maxima
#define WS_CNT_OFF  (WS_NEG_OFF + 3 * NB * 4)     // int[2]: arrive, done

// Agent-scope (device) memory ops: stores write through to the coherent
// point (cross-XCD visible WITHIN a kernel); loads bypass possibly-stale
// clean lines in the local L2.
__device__ __forceinline__ void agent_store_i32(int* p, int v) {
    __hip_atomic_store(p, v, __ATOMIC_RELAXED, __HIP_MEMORY_SCOPE_AGENT);
}
__device__ __forceinline__ void agent_store_f32(float* p, float v) {
    __hip_atomic_store(p, v, __ATOMIC_RELAXED, __HIP_MEMORY_SCOPE_AGENT);
}
__device__ __forceinline__ int agent_load_i32(const int* p) {
    return __hip_atomic_load(p, __ATOMIC_RELAXED, __HIP_MEMORY_SCOPE_AGENT);
}

// ONE kernel: phase 1 norm (2 rows/wave) -> grid barrier -> phase 2 gram
// (R6 structure: no B-LDS, direct L2 reads) -> last-block finalize.
// Theory (R7): the ~25 us that was invariant to every internal change in
// R0-R6 is the 3-4 dispatch boundaries (launch + 8-XCD cache flush each).
// Co-residency: 768 blocks @ 512 thr, <=64 VGPR (launch_bounds(512,8);
// R5 measured this phase-2 code at 52) -> 4 blocks/CU capacity >= 3 needed.
// Poll timeout converts any residency surprise into absmax-fail, not hang.
__global__ __launch_bounds__(512, 8) void mega_kernel(
        const float* __restrict__ anchor,
        const float* __restrict__ positive,
        const int* __restrict__ labels,
        unsigned char* __restrict__ F2,
        float* __restrict__ posArr,
        int* __restrict__ negmax,
        int* __restrict__ cnt,
        float* __restrict__ out) {
    __shared__ int slab[COLS_PER_CHUNK];          // 1 KB column labels
    __shared__ int lastFlag;
    __shared__ float wsum[8];

    int tid = threadIdx.x;
    int wid = tid >> 6, lane = tid & 63;

    // ---- negmax sentinel init: 16 entries per block (12288 total),
    // agent stores so they are coherent-point-visible before any atomicMax.
    if (tid < 16) agent_store_i32(&negmax[blockIdx.x * 16 + tid], IMIN_SENT);

    // ================= Phase 1: normalize 2 rows per wave =================
    {
        int kk = lane >> 4, quad = (lane >> 2) & 3, jj = (lane & 3) * 4;
        #pragma unroll
        for (int i = 0; i < 2; ++i) {
            int row = blockIdx.x * 16 + wid * 2 + i;
            int group = row >> 4, r15 = row & 15;
            int* dst = (int*)(F2 + (size_t)group * 4096 + kk * 1024 + (quad * 16 + r15) * 16 + jj);

            if (row < NB) {
                const float* src = anchor + (size_t)row * ND;
                float4 x = *(const float4*)(src + lane * 4);
                float ss = x.x * x.x + x.y * x.y + x.z * x.z + x.w * x.w;
                #pragma unroll
                for (int m = 1; m < 64; m <<= 1) ss += __shfl_xor(ss, m, 64);
                float inv = 127.0f / fmaxf(sqrtf(ss), 1e-12f);
                int b0 = (int)rintf(x.x * inv) & 0xff;
                int b1 = (int)rintf(x.y * inv) & 0xff;
                int b2 = (int)rintf(x.z * inv) & 0xff;
                int b3 = (int)rintf(x.w * inv) & 0xff;
                agent_store_i32(dst, b0 | (b1 << 8) | (b2 << 16) | (b3 << 24));
            } else {
                int q = row - NB;
                int v = q >> 12;                 // 0 or 1
                int j = q & (NB - 1);
                const float* sp = positive + (size_t)(j * NP + v) * ND;
                const float* sa = anchor + (size_t)j * ND;
                float4 xp = *(const float4*)(sp + lane * 4);
                float4 xa = *(const float4*)(sa + lane * 4);
                float sspv = xp.x * xp.x + xp.y * xp.y + xp.z * xp.z + xp.w * xp.w;
                float ssa  = xa.x * xa.x + xa.y * xa.y + xa.z * xa.z + xa.w * xa.w;
                float dot  = xa.x * xp.x + xa.y * xp.y + xa.z * xp.z + xa.w * xp.w;
                #pragma unroll
                for (int m = 1; m < 64; m <<= 1) {
                    sspv += __shfl_xor(sspv, m, 64);
                    ssa  += __shfl_xor(ssa, m, 64);
                    dot  += __shfl_xor(dot, m, 64);
                }
                float invp = 127.0f / fmaxf(sqrtf(sspv), 1e-12f);
                int b0 = (int)rintf(xp.x * invp) & 0xff;
                int b1 = (int)rintf(xp.y * invp) & 0xff;
                int b2 = (int)rintf(xp.z * invp) & 0xff;
                int b3 = (int)rintf(xp.w * invp) & 0xff;
                agent_store_i32(dst, b0 | (b1 << 8) | (b2 << 16) | (b3 << 24));
                if (lane == 0) {
                    float inva = 1.0f / fmaxf(sqrtf(ssa), 1e-12f);
                    float invpf = invp * (1.0f / 127.0f);
                    float dn = dot * inva * invpf;
                    float sq = 2.0f - 2.0f * dn;
                    agent_store_f32(&posArr[j * NP + v], sqrtf(fmaxf(sq, 1e-12f)));
                }
            }
        }
    }

    // ================= Grid-wide barrier (arrive + spin) =================
    __syncthreads();                              // all waves' stores drained (vmcnt 0)
    if (tid == 0) {
        atomicAdd(&cnt[0], 1);                    // device-scope arrive
        int polls = 0;
        while (agent_load_i32(&cnt[0]) < NBLK && polls < (1 << 22)) {
            __builtin_amdgcn_s_sleep(2);
            ++polls;                              // timeout -> wrong result, not hang
        }
    }
    __syncthreads();                              // release whole block

    // ================= Phase 2: masked-max Gram (R6 verbatim) =============
    int l15 = lane & 15, quad = lane >> 4;
    int id = blockIdx.x;                          // 0..767
    int chunk = id >> 4;                          // 0..47
    int rbi   = id & 15;                          // 0..15 row-block index
    int rowBase = rbi * 256 + wid * 32;           // 32 rows per wave
    int col0 = chunk * COLS_PER_CHUNK;
    int part = chunk >> 4;                        // 0=aa, 1=p0, 2=p1

    // A preload (b128): groups rbi*16 + wid*2 + s.
    i32x4 af[2][4];
    #pragma unroll
    for (int s = 0; s < 2; ++s) {
        const unsigned char* ab = F2 + (size_t)(rbi * 16 + wid * 2 + s) * 4096 + lane * 16;
        #pragma unroll
        for (int kk = 0; kk < 4; ++kk)
            af[s][kk] = *(const i32x4*)(ab + kk * 1024);
    }
    unsigned rlp[2];
    #pragma unroll
    for (int s = 0; s < 2; ++s) {
        const int* lb = labels + rowBase + s * 16 + quad * 4;
        rlp[s] = (unsigned)lb[0] | ((unsigned)lb[1] << 8)
               | ((unsigned)lb[2] << 16) | ((unsigned)lb[3] << 24);
    }
    if (tid < COLS_PER_CHUNK) slab[tid] = labels[(col0 & (NB - 1)) + tid];

    int vmax[2][4];
    #pragma unroll
    for (int s = 0; s < 2; ++s)
        #pragma unroll
        for (int r = 0; r < 4; ++r) vmax[s][r] = IMIN_SENT;

    __syncthreads();                              // slab visibility

    const unsigned char* bbase = F2 + (size_t)chunk * 65536 + lane * 16;
    #pragma unroll 2
    for (int ct = 0; ct < TILES; ++ct) {
        i32x4 bfr[4];
        #pragma unroll
        for (int kk = 0; kk < 4; ++kk)
            bfr[kk] = *(const i32x4*)(bbase + ct * 4096 + kk * 1024);

        int lc = slab[ct * 16 + l15];
        unsigned lcq = (unsigned)lc * 0x01010101u;

        i32x4 acc[2];
        #pragma unroll
        for (int s = 0; s < 2; ++s) acc[s] = (i32x4){0, 0, 0, 0};
        #pragma unroll
        for (int kk = 0; kk < 4; ++kk)
            #pragma unroll
            for (int s = 0; s < 2; ++s)
                acc[s] = __builtin_amdgcn_mfma_i32_16x16x64_i8(af[s][kk], bfr[kk], acc[s], 0, 0, 0);

        #pragma unroll
        for (int s = 0; s < 2; ++s) {
            unsigned x = rlp[s] ^ lcq;            // byte r == 0 iff labels equal
            #pragma unroll
            for (int r = 0; r < 4; ++r) {
                bool neq = ((x >> (8 * r)) & 0xffu) != 0u;
                int cand = neq ? acc[s][r] : IMIN_SENT;
                vmax[s][r] = vmax[s][r] > cand ? vmax[s][r] : cand;
            }
        }
    }

    #pragma unroll
    for (int m = 1; m < 16; m <<= 1)
        #pragma unroll
        for (int s = 0; s < 2; ++s)
            #pragma unroll
            for (int r = 0; r < 4; ++r) {
                int o = __shfl_xor(vmax[s][r], m, 64);
                vmax[s][r] = vmax[s][r] > o ? vmax[s][r] : o;
            }

    if (l15 == 0) {
        #pragma unroll
        for (int s = 0; s < 2; ++s)
            #pragma unroll
            for (int r = 0; r < 4; ++r) {
                int row = rowBase + s * 16 + quad * 4 + r;
                atomicMax(&negmax[part * NB + row], vmax[s][r]);
            }
    }

    // ================= Last-block finalize (no fences) ====================
    // atomicMax ops execute at the coherent point; __syncthreads drains
    // this block's vmcnt before the done-count, and agent loads read the
    // coherent point directly -- no threadfence/wbL2 anywhere (R5's poison).
    __syncthreads();
    if (tid == 0) lastFlag = (atomicAdd(&cnt[1], 1) == NBLK - 1);
    __syncthreads();
    if (!lastFlag) return;

    float lsum = 0.0f;
    #pragma unroll
    for (int k = 0; k < 8; ++k) {
        int row = tid + k * 512;
        int ia = agent_load_i32(&negmax[row]);
        int i0 = agent_load_i32(&negmax[NB + row]);
        int i1 = agent_load_i32(&negmax[2 * NB + row]);
        int m0 = ia > i0 ? ia : i0;
        int m1 = ia > i1 ? ia : i1;
        // Sentinel path: all-masked row stays IMIN_SENT -> huge neg distance
        // -> hinge clamps to 0, matching the inf reference.
        float d0 = (float)m0 * INV_SCALE;
        float d1 = (float)m1 * INV_SCALE;
        float n0 = sqrtf(fmaxf(2.0f - 2.0f * d0, 1e-12f));
        float n1 = sqrtf(fmaxf(2.0f - 2.0f * d1, 1e-12f));
        float2 pr = *(const float2*)&posArr[row * 2];
        lsum += fmaxf(pr.x - n0 + 1.0f, 0.0f) + fmaxf(pr.y - n1 + 1.0f, 0.0f);
    }
    #pragma unroll
    for (int m = 1; m < 64; m <<= 1) lsum += __shfl_xor(lsum, m, 64);
    if (lane == 0) wsum[wid] = lsum;
    __syncthreads();
    if (tid == 0) {
        float s = 0.0f;
        #pragma unroll
        for (int w = 0; w < 8; ++w) s += wsum[w];
        out[0] = s * (1.0f / (NB * NP));          // plain store; kernel-end flush
    }
}

extern "C" void kernel_launch(void* const* d_in, const int* in_sizes, int n_in,
                              void* d_out, int out_size, void* d_ws, size_t ws_size,
                              hipStream_t stream) {
    const float* anchor   = (const float*)d_in[0];
    const float* positive = (const float*)d_in[1];
    const int*   labels   = (const int*)d_in[2];
    float* out = (float*)d_out;

    unsigned char* F2 = (unsigned char*)((char*)d_ws + WS_F_OFF);
    float* posArr     = (float*)((char*)d_ws + WS_POS_OFF);
    int*   negmax     = (int*)((char*)d_ws + WS_NEG_OFF);
    int*   cnt        = (int*)((char*)d_ws + WS_CNT_OFF);

    hipMemsetAsync(cnt, 0, 2 * sizeof(int), stream);   // zero arrive/done counters
    mega_kernel<<<NBLK, 512, 0, stream>>>(anchor, positive, labels,
                                          F2, posArr, negmax, cnt, out);
}

// Round 10
// 88.037 us; speedup vs baseline: 1.7129x; 1.7129x over previous
//
#include <hip/hip_runtime.h>
#include <hip/hip_bf16.h>

// Problem constants
#define NB    4096          // batch
#define ND    256           // dim
#define NP    2             // positives per anchor
#define TOT   (NB * 3)      // 12288 rows: [a | p0 | p1]
#define NCHUNK 48           // 3 parts x 16 chunks; each chunk within one part
#define COLS_PER_CHUNK 256
#define TILES 16
#define IMIN_SENT (-1073741824)      // mask sentinel; < any dot (|dot| <= 4.13M)
#define INV_SCALE (1.0f / 16129.0f)  // 1/(127*127)

// F2 is FRAGMENT-MAJOR i8 (R13 layout): for 16-row group g, K-block kk (64
// i8), the 1024-B block F2[g*4096 + kk*1024 + (quad*16 + r15)*16 + j] holds
// K-byte kk*64 + quad*16 + j of row g*16 + r15. Fragment loads = lane*16
// contiguous b128.
typedef float f32x4 __attribute__((ext_vector_type(4)));
typedef int   i32x4 __attribute__((ext_vector_type(4)));

// ws layout (bytes)
#define WS_F_OFF    0                             // uchar[3 MB] i8 fragment-major
#define WS_POS_OFF  (TOT * 256)                   // float[4096*2] pos distances
#define WS_NEG_OFF  (WS_POS_OFF + NB * NP * 4)    // int[3][4096] neg-dot maxima

// Kernel 1: normalize rows of [a | p0 | p1] -> i8 (x127), fragment-major;
// p-rows also emit the exact fp32 positive distance. One wave per row.
// Blocks 0..47 additionally initialize negmax to the sentinel (stream-ordered
// before gram, so no reliance on workspace poison). R2-exact.
__global__ void norm_pos_kernel(const float* __restrict__ anchor,
                                const float* __restrict__ positive,
                                unsigned char* __restrict__ F2,
                                float* __restrict__ posArr,
                                int* __restrict__ negmax) {
    if (blockIdx.x < 48) negmax[blockIdx.x * 256 + threadIdx.x] = IMIN_SENT;

    int wid = threadIdx.x >> 6, lane = threadIdx.x & 63;
    int row = blockIdx.x * 4 + wid;              // grid = 3072
    int group = row >> 4, r15 = row & 15;
    int kk = lane >> 4, quad = (lane >> 2) & 3, jj = (lane & 3) * 4;
    int* dst = (int*)(F2 + (size_t)group * 4096 + kk * 1024 + (quad * 16 + r15) * 16 + jj);

    if (row < NB) {
        const float* src = anchor + (size_t)row * ND;
        float4 x = *(const float4*)(src + lane * 4);
        float ss = x.x * x.x + x.y * x.y + x.z * x.z + x.w * x.w;
        #pragma unroll
        for (int m = 1; m < 64; m <<= 1) ss += __shfl_xor(ss, m, 64);
        float inv = 127.0f / fmaxf(sqrtf(ss), 1e-12f);
        int b0 = (int)rintf(x.x * inv) & 0xff;
        int b1 = (int)rintf(x.y * inv) & 0xff;
        int b2 = (int)rintf(x.z * inv) & 0xff;
        int b3 = (int)rintf(x.w * inv) & 0xff;
        *dst = b0 | (b1 << 8) | (b2 << 16) | (b3 << 24);
    } else {
        int q = row - NB;
        int v = q >> 12;                         // 0 or 1
        int j = q & (NB - 1);
        const float* sp = positive + (size_t)(j * NP + v) * ND;
        const float* sa = anchor + (size_t)j * ND;
        float4 xp = *(const float4*)(sp + lane * 4);
        float4 xa = *(const float4*)(sa + lane * 4);
        float sspv = xp.x * xp.x + xp.y * xp.y + xp.z * xp.z + xp.w * xp.w;
        float ssa  = xa.x * xa.x + xa.y * xa.y + xa.z * xa.z + xa.w * xa.w;
        float dot  = xa.x * xp.x + xa.y * xp.y + xa.z * xp.z + xa.w * xp.w;
        #pragma unroll
        for (int m = 1; m < 64; m <<= 1) {
            sspv += __shfl_xor(sspv, m, 64);
            ssa  += __shfl_xor(ssa, m, 64);
            dot  += __shfl_xor(dot, m, 64);
        }
        float invp = 127.0f / fmaxf(sqrtf(sspv), 1e-12f);
        int b0 = (int)rintf(xp.x * invp) & 0xff;
        int b1 = (int)rintf(xp.y * invp) & 0xff;
        int b2 = (int)rintf(xp.z * invp) & 0xff;
        int b3 = (int)rintf(xp.w * invp) & 0xff;
        *dst = b0 | (b1 << 8) | (b2 << 16) | (b3 << 24);
        if (lane == 0) {
            float inva = 1.0f / fmaxf(sqrtf(ssa), 1e-12f);
            float invpf = invp * (1.0f / 127.0f);
            float dn = dot * inva * invpf;
            float sq = 2.0f - 2.0f * dn;
            posArr[j * NP + v] = sqrtf(fmaxf(sq, 1e-12f));
        }
    }
}

// Tile compute: 8 MFMA (2 row-groups x 4 K-blocks) + label-mask fold,
// wrapped in s_setprio(1)/(0). __forceinline__ + constant indices after
// inlining -> all arrays stay in registers (no dynamic indexing).
__device__ __forceinline__ void mfma_fold(const i32x4 af[2][4],
                                          const i32x4 buf[4],
                                          int lc, unsigned rlp0, unsigned rlp1,
                                          int vmax[2][4]) {
    unsigned lcq = (unsigned)lc * 0x01010101u;
    i32x4 acc0 = (i32x4){0, 0, 0, 0};
    i32x4 acc1 = (i32x4){0, 0, 0, 0};
    __builtin_amdgcn_s_setprio(1);
    #pragma unroll
    for (int kk = 0; kk < 4; ++kk) {
        acc0 = __builtin_amdgcn_mfma_i32_16x16x64_i8(af[0][kk], buf[kk], acc0, 0, 0, 0);
        acc1 = __builtin_amdgcn_mfma_i32_16x16x64_i8(af[1][kk], buf[kk], acc1, 0, 0, 0);
    }
    __builtin_amdgcn_s_setprio(0);
    unsigned x0 = rlp0 ^ lcq;
    unsigned x1 = rlp1 ^ lcq;
    #pragma unroll
    for (int r = 0; r < 4; ++r) {
        bool nq0 = ((x0 >> (8 * r)) & 0xffu) != 0u;
        bool nq1 = ((x1 >> (8 * r)) & 0xffu) != 0u;
        int c0 = nq0 ? acc0[r] : IMIN_SENT;
        int c1 = nq1 ? acc1[r] : IMIN_SENT;
        vmax[0][r] = vmax[0][r] > c0 ? vmax[0][r] : c0;
        vmax[1][r] = vmax[1][r] > c1 ? vmax[1][r] : c1;
    }
}

// Kernel 2: fused masked-max Gram, INT8 (R6 no-B-LDS base). R8 experiment,
// third submission (two infra-failed rounds, zero data); macro replaced by
// an inline function to de-risk toolchain issues -- variables unchanged:
//  - K-loop software-pipelined with NAMED register double-buffers bA/bB:
//    tile ct+1's 4 global b128 loads issue BEFORE tile ct's MFMA cluster,
//    so the compiler's auto-waitcnt is vmcnt(4), not a full drain -- the
//    per-tile L2 latency exposure (the last unprobed mechanism shared by
//    ALL ~30 us gram variants) hides under the previous tile's compute.
//  - s_setprio(1) around each MFMA cluster (T5): valid because the K-loop
//    is barrier-free -> resident waves are phase-diverse.
__global__ __launch_bounds__(512) void gram_max_kernel(
        const unsigned char* __restrict__ F2,
        const int* __restrict__ labels,
        int* __restrict__ negmax) {
    __shared__ int slab[COLS_PER_CHUNK];          // 1 KB column labels
    int tid = threadIdx.x;
    int wid = tid >> 6, lane = tid & 63;
    int l15 = lane & 15, quad = lane >> 4;

    int id = blockIdx.x;                         // 0..767
    int chunk = id >> 4;                         // 0..47
    int rbi   = id & 15;                         // 0..15 row-block index

    int rowBase = rbi * 256 + wid * 32;          // 32 rows per wave
    int col0 = chunk * COLS_PER_CHUNK;
    int part = chunk >> 4;                       // 0=aa, 1=p0, 2=p1

    // ---- A preload (b128, 1 KB/wave-load): groups rbi*16 + wid*2 + s.
    i32x4 af[2][4];
    #pragma unroll
    for (int s = 0; s < 2; ++s) {
        const unsigned char* ab = F2 + (size_t)(rbi * 16 + wid * 2 + s) * 4096 + lane * 16;
        #pragma unroll
        for (int kk = 0; kk < 4; ++kk)
            af[s][kk] = *(const i32x4*)(ab + kk * 1024);
    }
    // Row labels, byte-packed (labels < 200 fit a byte). C row = quad*4+r.
    unsigned rlp[2];
    #pragma unroll
    for (int s = 0; s < 2; ++s) {
        const int* lb = labels + rowBase + s * 16 + quad * 4;
        rlp[s] = (unsigned)lb[0] | ((unsigned)lb[1] << 8)
               | ((unsigned)lb[2] << 16) | ((unsigned)lb[3] << 24);
    }
    if (tid < COLS_PER_CHUNK) slab[tid] = labels[(col0 & (NB - 1)) + tid];

    int vmax[2][4];
    #pragma unroll
    for (int s = 0; s < 2; ++s)
        #pragma unroll
        for (int r = 0; r < 4; ++r) vmax[s][r] = IMIN_SENT;

    const unsigned char* bbase = F2 + (size_t)chunk * 65536 + lane * 16;

    // Prologue: load tile 0 into bA (overlaps the slab barrier).
    i32x4 bA[4], bB[4];
    #pragma unroll
    for (int kk = 0; kk < 4; ++kk)
        bA[kk] = *(const i32x4*)(bbase + kk * 1024);

    __syncthreads();   // slab visibility only

    // ---- Pipelined K-loop: issue next tile's loads, then MFMA current.
    #pragma unroll
    for (int ct = 0; ct < TILES; ct += 2) {
        // issue loads for tile ct+1 into bB
        #pragma unroll
        for (int kk = 0; kk < 4; ++kk)
            bB[kk] = *(const i32x4*)(bbase + (ct + 1) * 4096 + kk * 1024);
        // compute tile ct from bA (waitcnt here leaves bB in flight)
        mfma_fold(af, bA, slab[ct * 16 + l15], rlp[0], rlp[1], vmax);
        // issue loads for tile ct+2 into bA (except last pair)
        if (ct + 2 < TILES) {
            #pragma unroll
            for (int kk = 0; kk < 4; ++kk)
                bA[kk] = *(const i32x4*)(bbase + (ct + 2) * 4096 + kk * 1024);
        }
        // compute tile ct+1 from bB
        mfma_fold(af, bB, slab[(ct + 1) * 16 + l15], rlp[0], rlp[1], vmax);
    }

    // Reduce max across the 16 column-lanes (same quad = same rows)
    #pragma unroll
    for (int m = 1; m < 16; m <<= 1)
        #pragma unroll
        for (int s = 0; s < 2; ++s)
            #pragma unroll
            for (int r = 0; r < 4; ++r) {
                int o = __shfl_xor(vmax[s][r], m, 64);
                vmax[s][r] = vmax[s][r] > o ? vmax[s][r] : o;
            }

    if (l15 == 0) {
        #pragma unroll
        for (int s = 0; s < 2; ++s)
            #pragma unroll
            for (int r = 0; r < 4; ++r) {
                int row = rowBase + s * 16 + quad * 4 + r;
                atomicMax(&negmax[part * NB + row], vmax[s][r]);
            }
    }
}

// Kernel 3: ONE block, 512 threads: negmax ints -> neg distances -> hinge
// -> mean -> plain store to out[0]. No d_out memset dispatch needed.
__global__ __launch_bounds__(512) void finalize_kernel(
        const int* __restrict__ negmax,
        const float* __restrict__ posArr,
        float* __restrict__ out) {
    int tid = threadIdx.x;
    float lsum = 0.0f;
    #pragma unroll
    for (int k = 0; k < 8; ++k) {
        int row = tid + k * 512;
        int ia = negmax[row];
        int i0 = negmax[NB + row];
        int i1 = negmax[2 * NB + row];
        int m0 = ia > i0 ? ia : i0;
        int m1 = ia > i1 ? ia : i1;
        // Sentinel path: all-masked row stays IMIN_SENT -> huge neg distance
        // -> hinge clamps to 0, matching the inf reference.
        float d0 = (float)m0 * INV_SCALE;
        float d1 = (float)m1 * INV_SCALE;
        float n0 = sqrtf(fmaxf(2.0f - 2.0f * d0, 1e-12f));
        float n1 = sqrtf(fmaxf(2.0f - 2.0f * d1, 1e-12f));
        float2 pr = *(const float2*)&posArr[row * 2];
        lsum += fmaxf(pr.x - n0 + 1.0f, 0.0f) + fmaxf(pr.y - n1 + 1.0f, 0.0f);
    }
    int lane = tid & 63, wid = tid >> 6;
    #pragma unroll
    for (int m = 1; m < 64; m <<= 1) lsum += __shfl_xor(lsum, m, 64);
    __shared__ float wsum[8];
    if (lane == 0) wsum[wid] = lsum;
    __syncthreads();
    if (tid == 0) {
        float s = 0.0f;
        #pragma unroll
        for (int w = 0; w < 8; ++w) s += wsum[w];
        out[0] = s * (1.0f / (NB * NP));
    }
}

extern "C" void kernel_launch(void* const* d_in, const int* in_sizes, int n_in,
                              void* d_out, int out_size, void* d_ws, size_t ws_size,
                              hipStream_t stream) {
    const float* anchor   = (const float*)d_in[0];
    const float* positive = (const float*)d_in[1];
    const int*   labels   = (const int*)d_in[2];
    float* out = (float*)d_out;

    unsigned char* F2 = (unsigned char*)((char*)d_ws + WS_F_OFF);
    float* posArr     = (float*)((char*)d_ws + WS_POS_OFF);
    int*   negmax     = (int*)((char*)d_ws + WS_NEG_OFF);

    norm_pos_kernel<<<TOT / 4, 256, 0, stream>>>(anchor, positive, F2, posArr, negmax);
    gram_max_kernel<<<(NB / 256) * NCHUNK, 512, 0, stream>>>(F2, labels, negmax);
    finalize_kernel<<<1, 512, 0, stream>>>(negmax, posArr, out);
}